// Round 4
// baseline (1570.845 us; speedup 1.0000x reference)
//
#include <hip/hip_runtime.h>
#include <stdint.h>

typedef __attribute__((ext_vector_type(8))) short bfx8;   // 8 bf16 in 4 VGPRs
typedef __attribute__((ext_vector_type(4))) float f32x4;  // MFMA accumulator

// ---------- bf16 helpers (bit-level, RNE) ----------
__device__ __forceinline__ float bf2f(unsigned short u){
  union { unsigned int i; float f; } x; x.i = ((unsigned int)u) << 16; return x.f;
}
__device__ __forceinline__ unsigned short f2bf(float f){
  union { float f; unsigned int i; } x; x.f = f;
  unsigned int r = x.i + 0x7fff + ((x.i >> 16) & 1);
  return (unsigned short)(r >> 16);
}
__device__ __forceinline__ void unpack8(uint4 v, float* o){
  o[0]=bf2f((unsigned short)(v.x)); o[1]=bf2f((unsigned short)(v.x>>16));
  o[2]=bf2f((unsigned short)(v.y)); o[3]=bf2f((unsigned short)(v.y>>16));
  o[4]=bf2f((unsigned short)(v.z)); o[5]=bf2f((unsigned short)(v.z>>16));
  o[6]=bf2f((unsigned short)(v.w)); o[7]=bf2f((unsigned short)(v.w>>16));
}
__device__ __forceinline__ uint4 pack8(const float* f){
  uint4 v;
  v.x = (unsigned)f2bf(f[0]) | ((unsigned)f2bf(f[1])<<16);
  v.y = (unsigned)f2bf(f[2]) | ((unsigned)f2bf(f[3])<<16);
  v.z = (unsigned)f2bf(f[4]) | ((unsigned)f2bf(f[5])<<16);
  v.w = (unsigned)f2bf(f[6]) | ((unsigned)f2bf(f[7])<<16);
  return v;
}
__device__ __forceinline__ void loadrow16_f32(const float* p, float* in){
  float4 a = *(const float4*)p;      float4 b = *(const float4*)(p+4);
  float4 c = *(const float4*)(p+8);  float4 d = *(const float4*)(p+12);
  in[0]=a.x; in[1]=a.y; in[2]=a.z; in[3]=a.w;
  in[4]=b.x; in[5]=b.y; in[6]=b.z; in[7]=b.w;
  in[8]=c.x; in[9]=c.y; in[10]=c.z; in[11]=c.w;
  in[12]=d.x; in[13]=d.y; in[14]=d.z; in[15]=d.w;
}
// 8 contiguous f32 * m -> bf16x8
__device__ __forceinline__ bfx8 f32x8_to_bf(const float* p, float m){
  float4 a = *(const float4*)p; float4 b = *(const float4*)(p+4);
  bfx8 r;
  r[0]=(short)f2bf(a.x*m); r[1]=(short)f2bf(a.y*m); r[2]=(short)f2bf(a.z*m); r[3]=(short)f2bf(a.w*m);
  r[4]=(short)f2bf(b.x*m); r[5]=(short)f2bf(b.y*m); r[6]=(short)f2bf(b.z*m); r[7]=(short)f2bf(b.w*m);
  return r;
}

// ---------- f32 -> packed bf16 conversion (8 elems/thread) ----------
__global__ void k_f2b(const float* __restrict__ src, unsigned short* __restrict__ dst, long n8){
  long t = (long)blockIdx.x*blockDim.x + threadIdx.x;
  if (t >= n8) return;
  const float* p = src + t*8;
  float4 a = *(const float4*)p; float4 b = *(const float4*)(p+4);
  float f[8] = {a.x,a.y,a.z,a.w,b.x,b.y,b.z,b.w};
  *(uint4*)(dst + t*8) = pack8(f);
}

// ---------- bucketed CSR build ----------
__global__ void __launch_bounds__(256) k_bcount(
    const int* __restrict__ dst, int n, int chunk, int shift, int nb,
    int* __restrict__ bkt_cnt){
  extern __shared__ int hist[];
  for (int b = threadIdx.x; b < nb; b += 256) hist[b] = 0;
  __syncthreads();
  int i0 = blockIdx.x * chunk;
  int iend = min(i0 + chunk, n);
  for (int i = i0 + threadIdx.x; i < iend; i += 256)
    atomicAdd(&hist[dst[i] >> shift], 1);
  __syncthreads();
  for (int b = threadIdx.x; b < nb; b += 256){
    int h = hist[b];
    if (h) atomicAdd(&bkt_cnt[b], h);
  }
}

__global__ void k_bscan(const int* __restrict__ bkt_cnt, int* __restrict__ bkt_base,
                        int* __restrict__ bcur, int nb){
  __shared__ int s[256];
  __shared__ int carry;
  if (threadIdx.x==0) carry = 0;
  __syncthreads();
  for (int base=0; base<nb; base+=256){
    int i = base + threadIdx.x;
    int v = (i<nb) ? bkt_cnt[i] : 0;
    s[threadIdx.x] = v; __syncthreads();
    for (int off=1; off<256; off<<=1){
      int t = (threadIdx.x>=off) ? s[threadIdx.x-off] : 0;
      __syncthreads();
      s[threadIdx.x] += t;
      __syncthreads();
    }
    int excl = s[threadIdx.x] - v + carry;
    if (i<nb){ bkt_base[i] = excl; bcur[i*16] = excl; }
    int tot = s[255];
    __syncthreads();
    if (threadIdx.x==0) carry += tot;
    __syncthreads();
  }
  if (threadIdx.x==0) bkt_base[nb] = carry;
}

// scatter with block-local counting sort: writes to each bucket run are
// emitted by consecutive threads at consecutive addresses (line-filling).
// PAY=2: (dst,src) int2; PAY=4: (dst,src,eid,0) int4.
template<int PAY, int CHUNK, int NBMAX>
__global__ void __launch_bounds__(256) k_scatter2(
    const int* __restrict__ src, const int* __restrict__ dst, int n,
    int shift, int nb, int* __restrict__ bcur, int* __restrict__ out){
  __shared__ int hist[NBMAX];   // counts -> cursor (local base)
  __shared__ int delta[NBMAX];  // global run base - local base
  __shared__ int s[256];
  __shared__ int slot[CHUNK];   // edge id in bucket-grouped order
  __shared__ int carry;
  for (int b = threadIdx.x; b < nb; b += 256) hist[b] = 0;
  if (threadIdx.x==0) carry = 0;
  __syncthreads();
  int i0 = blockIdx.x * CHUNK;
  int iend = min(i0 + CHUNK, n);
  for (int i = i0 + threadIdx.x; i < iend; i += 256)
    atomicAdd(&hist[dst[i] >> shift], 1);
  __syncthreads();
  // exclusive scan of hist -> local bases; reserve global runs; delta
  for (int base = 0; base < nb; base += 256){
    int b = base + threadIdx.x;
    int v = (b < nb) ? hist[b] : 0;
    s[threadIdx.x] = v; __syncthreads();
    for (int off=1; off<256; off<<=1){
      int t = (threadIdx.x>=off) ? s[threadIdx.x-off] : 0;
      __syncthreads();
      s[threadIdx.x] += t;
      __syncthreads();
    }
    int excl = s[threadIdx.x] - v + carry;
    int tot = s[255];
    if (b < nb){
      int g = v ? atomicAdd(&bcur[b*16], v) : 0;
      delta[b] = g - excl;
      hist[b] = excl;               // becomes the placement cursor
    }
    __syncthreads();
    if (threadIdx.x==0) carry += tot;
    __syncthreads();
  }
  // place edge ids into bucket-grouped LDS order
  for (int i = i0 + threadIdx.x; i < iend; i += 256){
    int b = dst[i] >> shift;
    int p = atomicAdd(&hist[b], 1);
    slot[p] = i;
  }
  __syncthreads();
  // streaming write: consecutive j -> consecutive addresses within runs
  int cnt = iend - i0;
  for (int j = threadIdx.x; j < cnt; j += 256){
    int i = slot[j];
    int d = dst[i];               // chunk-resident re-read (L1)
    int b = d >> shift;
    int a = j + delta[b];
    if (PAY == 2) *(int2*)(out + (size_t)a*2) = make_int2(d, src[i]);
    else          *(int4*)(out + (size_t)a*4) = make_int4(d, src[i], i, 0);
  }
}

template<bool EID, int RLOG>
__global__ void __launch_bounds__(256) k_place2(
    const int* __restrict__ bkt_base, const int* __restrict__ binned,
    int nrows, int* __restrict__ rowptr,
    int* __restrict__ colA, int* __restrict__ colB){
  constexpr int R = 1 << RLOG;
  constexpr int K = R / 256;
  __shared__ int cnt[R];
  __shared__ int s[256];
  int rowBase = blockIdx.x << RLOG;
  int nr = min(R, nrows - rowBase);
  int beg = bkt_base[blockIdx.x], end = bkt_base[blockIdx.x+1];
  #pragma unroll
  for (int k=0;k<K;k++) cnt[threadIdx.x + k*256] = 0;
  __syncthreads();
  for (int i = beg + threadIdx.x; i < end; i += 256){
    int d = EID ? ((const int4*)binned)[i].x : ((const int2*)binned)[i].x;
    atomicAdd(&cnt[d & (R-1)], 1);
  }
  __syncthreads();
  int myBase = threadIdx.x * K;
  int part = 0;
  #pragma unroll
  for (int k=0;k<K;k++) part += cnt[myBase+k];
  s[threadIdx.x] = part; __syncthreads();
  for (int off=1; off<256; off<<=1){
    int t = (threadIdx.x>=off) ? s[threadIdx.x-off] : 0;
    __syncthreads();
    s[threadIdx.x] += t;
    __syncthreads();
  }
  int run = s[threadIdx.x] - part + beg;
  #pragma unroll
  for (int k=0;k<K;k++){
    int idx = myBase + k;
    int c = cnt[idx];
    cnt[idx] = run;                       // becomes the placement cursor
    if (idx < nr) rowptr[rowBase + idx] = run;
    run += c;
  }
  if (blockIdx.x == gridDim.x-1 && threadIdx.x == 255) rowptr[nrows] = end;
  __syncthreads();
  for (int i = beg + threadIdx.x; i < end; i += 256){
    if (EID){
      int4 v = ((const int4*)binned)[i];
      int p = atomicAdd(&cnt[v.x & (R-1)], 1);
      colA[p] = v.y; colB[p] = v.z;
    } else {
      int2 v = ((const int2*)binned)[i];
      int p = atomicAdd(&cnt[v.x & (R-1)], 1);
      colA[p] = v.y;
    }
  }
}

// ---------- gather spmm (bf16 rows) ----------
// 2 threads per row, 8 channels (16B) each; 2-way unroll for gather ILP.
template<bool REMAP>
__global__ void __launch_bounds__(256) k_spmm(
    const int* __restrict__ rowptr, const int* __restrict__ col,
    const int* __restrict__ remap,
    const unsigned short* __restrict__ src, unsigned short* __restrict__ out, int nrows){
  int t = blockIdx.x*256 + threadIdx.x;
  int row = t >> 1, half = t & 1;
  if (row >= nrows) return;
  int beg = rowptr[row], end = rowptr[row+1];
  float acc[8] = {0,0,0,0,0,0,0,0};
  float acc2[8] = {0,0,0,0,0,0,0,0};
  const unsigned short* sp = src + (half<<3);
  int i = beg;
  for (; i+2 <= end; i += 2){
    int c0 = col[i], c1 = col[i+1];
    if (REMAP){ c0 = remap[c0]; c1 = remap[c1]; }
    uint4 v0 = *(const uint4*)(sp + ((size_t)c0<<4));
    uint4 v1 = *(const uint4*)(sp + ((size_t)c1<<4));
    float f0[8], f1[8]; unpack8(v0, f0); unpack8(v1, f1);
    #pragma unroll
    for (int j=0;j<8;j++){ acc[j] += f0[j]; acc2[j] += f1[j]; }
  }
  if (i < end){
    int c = col[i];
    if (REMAP) c = remap[c];
    uint4 v = *(const uint4*)(sp + ((size_t)c<<4));
    float f[8]; unpack8(v, f);
    #pragma unroll
    for (int j=0;j<8;j++) acc[j] += f[j];
  }
  #pragma unroll
  for (int j=0;j<8;j++) acc[j] += acc2[j];
  *(uint4*)(out + ((size_t)row<<4) + (half<<3)) = pack8(acc);
}

// ---------- fused 6-way projection via MFMA ----------
__global__ void __launch_bounds__(256) k_final_mfma(
    const float* __restrict__ base, const float* __restrict__ deg,
    const unsigned short* __restrict__ s2, const unsigned short* __restrict__ s3,
    const unsigned short* __restrict__ s4, const unsigned short* __restrict__ s5,
    const float* __restrict__ W, const float* __restrict__ Bb,
    float* __restrict__ hout, int nrows){
  int lane = threadIdx.x & 63;
  int l15 = lane & 15;
  int quad = lane >> 4;          // 0..3
  int kbase = quad * 8;          // 0,8,16,24 within the 32-wide k-block
  int slocal = kbase >> 4;       // source select within k-block (0 or 1)
  int k0 = kbase & 15;           // channel offset within source (0 or 8)

  bfx8 bh[3][2], bl[3][2];
  #pragma unroll
  for (int kb=0; kb<3; ++kb){
    int s = kb*2 + slocal;
    #pragma unroll
    for (int t=0;t<2;++t){
      int o = t*16 + l15;
      const float* wp = W + s*512 + o*16 + k0;
      bfx8 hi, lo;
      #pragma unroll
      for (int j=0;j<8;j++){
        float w0 = wp[j];
        unsigned short h = f2bf(w0);
        unsigned short l2 = f2bf(w0 - bf2f(h));
        hi[j] = (short)h; lo[j] = (short)l2;
      }
      bh[kb][t] = hi; bl[kb][t] = lo;
    }
  }
  float bias0 = 0.f, bias1 = 0.f;
  #pragma unroll
  for (int s=0;s<6;s++){ bias0 += Bb[s*32 + l15]; bias1 += Bb[s*32 + 16 + l15]; }

  int ntiles = (nrows + 15) >> 4;
  int wstart = (blockIdx.x<<2) + (threadIdx.x>>6);
  int wstep  = gridDim.x<<2;
  for (int tile = wstart; tile < ntiles; tile += wstep){
    int R0 = tile << 4;
    int row = R0 + l15;
    int rowc = min(row, nrows-1);
    size_t ro = (size_t)rowc*16 + k0;
    float m = slocal ? deg[rowc] : 1.f;
    bfx8 a0 = f32x8_to_bf(base + ro, m);
    bfx8 a1 = *(const bfx8*)((slocal ? s3 : s2) + ro);
    bfx8 a2 = *(const bfx8*)((slocal ? s5 : s4) + ro);
    f32x4 c0 = {bias0,bias0,bias0,bias0};
    f32x4 c1 = {bias1,bias1,bias1,bias1};
    c0 = __builtin_amdgcn_mfma_f32_16x16x32_bf16(a0, bh[0][0], c0, 0,0,0);
    c1 = __builtin_amdgcn_mfma_f32_16x16x32_bf16(a0, bh[0][1], c1, 0,0,0);
    c0 = __builtin_amdgcn_mfma_f32_16x16x32_bf16(a1, bh[1][0], c0, 0,0,0);
    c1 = __builtin_amdgcn_mfma_f32_16x16x32_bf16(a1, bh[1][1], c1, 0,0,0);
    c0 = __builtin_amdgcn_mfma_f32_16x16x32_bf16(a2, bh[2][0], c0, 0,0,0);
    c1 = __builtin_amdgcn_mfma_f32_16x16x32_bf16(a2, bh[2][1], c1, 0,0,0);
    c0 = __builtin_amdgcn_mfma_f32_16x16x32_bf16(a0, bl[0][0], c0, 0,0,0);
    c1 = __builtin_amdgcn_mfma_f32_16x16x32_bf16(a0, bl[0][1], c1, 0,0,0);
    c0 = __builtin_amdgcn_mfma_f32_16x16x32_bf16(a1, bl[1][0], c0, 0,0,0);
    c1 = __builtin_amdgcn_mfma_f32_16x16x32_bf16(a1, bl[1][1], c1, 0,0,0);
    c0 = __builtin_amdgcn_mfma_f32_16x16x32_bf16(a2, bl[2][0], c0, 0,0,0);
    c1 = __builtin_amdgcn_mfma_f32_16x16x32_bf16(a2, bl[2][1], c1, 0,0,0);
    #pragma unroll
    for (int j=0;j<4;j++){
      int r = R0 + quad*4 + j;
      if (r < nrows) hout[(size_t)r*16 + l15] = c0[j] + fmaxf(c1[j], 0.f);
    }
  }
}

// ---------- BN stats reduction over a row region ----------
__global__ void __launch_bounds__(256) k_red(
    const float* __restrict__ h, int nrows, float* __restrict__ stats){
  __shared__ float redS[4][16];
  __shared__ float redQ[4][16];
  float ssum[16], ssq[16];
  #pragma unroll
  for (int c=0;c<16;c++){ ssum[c]=0.f; ssq[c]=0.f; }
  for (long r = (long)blockIdx.x*256 + threadIdx.x; r < nrows; r += (long)gridDim.x*256){
    float in[16];
    loadrow16_f32(h + r*16, in);
    #pragma unroll
    for (int c=0;c<16;c++){ ssum[c] += in[c]; ssq[c] += in[c]*in[c]; }
  }
  int lane = threadIdx.x & 63, wid = threadIdx.x >> 6;
  #pragma unroll
  for (int c=0;c<16;c++){
    float s = ssum[c], q = ssq[c];
    for (int off=32; off; off>>=1){ s += __shfl_xor(s, off, 64); q += __shfl_xor(q, off, 64); }
    if (lane==0){ redS[wid][c] = s; redQ[wid][c] = q; }
  }
  __syncthreads();
  if (threadIdx.x < 16){
    float s=0.f, q=0.f;
    #pragma unroll
    for (int w4=0; w4<4; w4++){ s += redS[w4][threadIdx.x]; q += redQ[w4][threadIdx.x]; }
    atomicAdd(&stats[threadIdx.x], s);
    atomicAdd(&stats[16 + threadIdx.x], q);
  }
}

__global__ void k_stats(const float* __restrict__ st,
                        const float* __restrict__ wx, const float* __restrict__ bx,
                        const float* __restrict__ wy, const float* __restrict__ by,
                        float* __restrict__ prm, int nx, int ny){
  int c = threadIdx.x;
  if (c < 16){
    float m  = st[c]/(float)nx;
    float v  = st[16+c]/(float)nx - m*m;
    float sc = wx[c] * rsqrtf(v + 1e-5f);
    prm[c] = sc; prm[16+c] = bx[c] - m*sc;
    float m2  = st[32+c]/(float)ny;
    float v2  = st[48+c]/(float)ny - m2*m2;
    float sc2 = wy[c] * rsqrtf(v2 + 1e-5f);
    prm[32+c] = sc2; prm[48+c] = by[c] - m2*sc2;
  }
}

__global__ void k_norm(float* __restrict__ out, const float* __restrict__ prm,
                       long nx, long ntot){
  long g = ((long)blockIdx.x*256 + threadIdx.x) * 8;
  if (g >= ntot) return;
  const float* p = (g < nx) ? prm : prm + 32;
  int cbase = (int)(g & 15);
  float4 a = *(float4*)(out + g);
  float4 b = *(float4*)(out + g + 4);
  float f[8] = {a.x,a.y,a.z,a.w,b.x,b.y,b.z,b.w};
  #pragma unroll
  for (int j=0;j<8;j++){ int c = cbase + j; f[j] = f[j]*p[c] + p[16+c]; }
  *(float4*)(out + g)     = make_float4(f[0],f[1],f[2],f[3]);
  *(float4*)(out + g + 4) = make_float4(f[4],f[5],f[6],f[7]);
}

// ---------- host ----------
extern "C" void kernel_launch(void* const* d_in, const int* in_sizes, int n_in,
                              void* d_out, int out_size, void* d_ws, size_t ws_size,
                              hipStream_t stream){
  const float* x      = (const float*)d_in[0];
  const float* y      = (const float*)d_in[1];
  const float* deg_g  = (const float*)d_in[2];
  const float* deg_lg = (const float*)d_in[3];
  const float* thW    = (const float*)d_in[4];
  const float* thB    = (const float*)d_in[5];
  const float* gaW    = (const float*)d_in[6];
  const float* gaB    = (const float*)d_in[7];
  const float* bnxw   = (const float*)d_in[8];
  const float* bnxb   = (const float*)d_in[9];
  const float* bnyw   = (const float*)d_in[10];
  const float* bnyb   = (const float*)d_in[11];
  const int* src_g   = (const int*)d_in[12];
  const int* dst_g   = (const int*)d_in[13];
  const int* src_lg  = (const int*)d_in[14];
  const int* dst_lg  = (const int*)d_in[15];
  const int* eid2nid = (const int*)d_in[16];

  const int N  = in_sizes[2];   // deg_g is (N,1)
  const int E  = in_sizes[3];   // deg_lg is (E,1)
  const int EL = in_sizes[14];  // src_lg

  char* w = (char*)d_ws;
  auto alloc = [&](size_t bytes)->void*{
    void* p = (void*)w; w += (bytes + 255) & ~(size_t)255; return p;
  };
  int* g_rowptr   = (int*)alloc((size_t)(N+1)*4);
  int* g_col_src  = (int*)alloc((size_t)E*4);
  int* g_col_eid  = (int*)alloc((size_t)E*4);
  int* lg_rowptr  = (int*)alloc((size_t)(E+1)*4);
  int* lg_col     = (int*)alloc((size_t)EL*4);
  int* bcur       = (int*)alloc((size_t)1024*16*4);  // padded bucket cursors
  int* bkt_cnt_g  = (int*)alloc(1024*4);
  int* bkt_base_g = (int*)alloc(1025*4);
  int* bkt_cnt_l  = (int*)alloc(1024*4);
  int* bkt_base_l = (int*)alloc(1025*4);
  float* stats    = (float*)alloc(64*4);
  float* prm      = (float*)alloc(64*4);
  unsigned short* xb  = (unsigned short*)alloc((size_t)N*16*2);   // bf16 copy of x
  unsigned short* nz1 = (unsigned short*)alloc((size_t)N*16*2);
  unsigned short* nz2 = (unsigned short*)alloc((size_t)N*16*2);
  unsigned short* nz3 = (unsigned short*)alloc((size_t)N*16*2);
  unsigned short* nz4 = (unsigned short*)alloc((size_t)N*16*2);
  unsigned short* nyx = (unsigned short*)alloc((size_t)N*16*2);
  unsigned short* eb1 = (unsigned short*)alloc((size_t)E*16*2);
  unsigned short* eb2 = (unsigned short*)alloc((size_t)E*16*2);
  unsigned short* eb3 = (unsigned short*)alloc((size_t)E*16*2);  // B^3 y, then xy_agg
  unsigned short* yb  = (unsigned short*)alloc((size_t)E*16*2);  // bf16 copy of y; later reused as eb4
  unsigned short* eb4 = yb;            // alias: yb dead before eb4 is written
  int* binned_g = (int*)eb1;           // alias: E*16B   <= eb1 (E*32B)
  int* binned_l = (int*)eb2;           // alias: EL*8B   <= eb2 (E*32B)

  hipMemsetAsync(bkt_cnt_g, 0, 1024*4, stream);
  hipMemsetAsync(bkt_cnt_l, 0, 1024*4, stream);
  hipMemsetAsync(stats, 0, 64*4, stream);

  // ---- bf16 copies of x and y ----
  long nx8 = (long)N*16/8, ny8 = (long)E*16/8;
  k_f2b<<<(int)((nx8+255)/256), 256, 0, stream>>>(x, xb, nx8);
  k_f2b<<<(int)((ny8+255)/256), 256, 0, stream>>>(y, yb, ny8);

  // ---- bucketed CSR build: g (256 rows/bucket), payload (dst,src,eid,0) ----
  const int RLOG_G = 8;
  int nb_g = (N + (1<<RLOG_G) - 1) >> RLOG_G;            // ~391 buckets
  k_bcount<<<(E+8191)/8192, 256, (size_t)nb_g*4, stream>>>(
      dst_g, E, 8192, RLOG_G, nb_g, bkt_cnt_g);
  k_bscan<<<1, 256, 0, stream>>>(bkt_cnt_g, bkt_base_g, bcur, nb_g);
  k_scatter2<4, 4096, 512><<<(E+4095)/4096, 256, 0, stream>>>(
      src_g, dst_g, E, RLOG_G, nb_g, bcur, binned_g);
  k_place2<true, RLOG_G><<<nb_g, 256, 0, stream>>>(
      bkt_base_g, binned_g, N, g_rowptr, g_col_src, g_col_eid);

  // ---- bucketed CSR build: lg (2048 rows/bucket), payload (dst,src) ----
  const int RLOG_L = 11;
  int nb_l = (E + (1<<RLOG_L) - 1) >> RLOG_L;            // ~782 buckets
  k_bcount<<<(EL+16383)/16384, 256, (size_t)nb_l*4, stream>>>(
      dst_lg, EL, 16384, RLOG_L, nb_l, bkt_cnt_l);
  k_bscan<<<1, 256, 0, stream>>>(bkt_cnt_l, bkt_base_l, bcur, nb_l);
  k_scatter2<2, 16384, 1024><<<(EL+16383)/16384, 256, 0, stream>>>(
      src_lg, dst_lg, EL, RLOG_L, nb_l, bcur, binned_l);
  k_place2<false, RLOG_L><<<nb_l, 256, 0, stream>>>(
      bkt_base_l, binned_l, E, lg_rowptr, lg_col, (int*)nullptr);

  // ---- spmms that read yb first (so eb4 can reuse yb's buffer) ----
  int gs = (2*N+255)/256;
  int es = (2*E+255)/256;
  k_spmm<false><<<es, 256, 0, stream>>>(lg_rowptr, lg_col, nullptr, yb,  eb1, E);   // B y
  k_spmm<false><<<gs, 256, 0, stream>>>(g_rowptr, g_col_eid, nullptr, yb, nyx, N);  // sum_e y by dst
  // ---- node branch chain ----
  k_spmm<false><<<gs, 256, 0, stream>>>(g_rowptr, g_col_src, nullptr, xb,  nz1, N); // A x
  k_spmm<false><<<gs, 256, 0, stream>>>(g_rowptr, g_col_src, nullptr, nz1, nz2, N); // A^2 x
  k_spmm<false><<<gs, 256, 0, stream>>>(g_rowptr, g_col_src, nullptr, nz2, nz3, N); // A^3 x
  k_spmm<false><<<gs, 256, 0, stream>>>(g_rowptr, g_col_src, nullptr, nz3, nz4, N); // A^4 x
  // ---- edge branch chain (yb dead after eb1/nyx; eb4 overwrites it) ----
  k_spmm<false><<<es, 256, 0, stream>>>(lg_rowptr, lg_col, nullptr, eb1, eb2, E);   // B^2 y
  k_spmm<false><<<es, 256, 0, stream>>>(lg_rowptr, lg_col, nullptr, eb2, eb3, E);   // B^3 y
  k_spmm<false><<<es, 256, 0, stream>>>(lg_rowptr, lg_col, nullptr, eb3, eb4, E);   // B^4 y
  k_spmm<true><<<es, 256, 0, stream>>>(lg_rowptr, lg_col, eid2nid, xb,  eb3, E);    // B (x[eid2nid])

  // ---- fused projections + h (MFMA) ----
  float* outp = (float*)d_out;
  int tg = (N + 15) >> 4;  int bg2 = (tg + 3) / 4;  if (bg2 > 2048) bg2 = 2048;
  int te = (E + 15) >> 4;  int be2 = (te + 3) / 4;  if (be2 > 2048) be2 = 2048;
  k_final_mfma<<<bg2, 256, 0, stream>>>(x, deg_g, nyx, nz1, nz2, nz4,
                                        thW, thB, outp, N);
  k_final_mfma<<<be2, 256, 0, stream>>>(y, deg_lg, eb3, eb1, eb2, eb4,
                                        gaW, gaB, outp + (size_t)N*16, E);

  // ---- BN stats + normalize ----
  k_red<<<512, 256, 0, stream>>>(outp, N, stats);
  k_red<<<512, 256, 0, stream>>>(outp + (size_t)N*16, E, stats + 32);
  k_stats<<<1, 64, 0, stream>>>(stats, bnxw, bnxb, bnyw, bnyb, prm, N, E);
  long ntot = (long)(N + E) * 16;
  k_norm<<<(int)((ntot/8 + 255)/256), 256, 0, stream>>>(outp, prm, (long)N*16, ntot);
}

// Round 5
// 1506.829 us; speedup vs baseline: 1.0425x; 1.0425x over previous
//
#include <hip/hip_runtime.h>
#include <stdint.h>

typedef __attribute__((ext_vector_type(8))) short bfx8;   // 8 bf16 in 4 VGPRs
typedef __attribute__((ext_vector_type(4))) float f32x4;  // MFMA accumulator

// ---------- bf16 helpers (bit-level, RNE) ----------
__device__ __forceinline__ float bf2f(unsigned short u){
  union { unsigned int i; float f; } x; x.i = ((unsigned int)u) << 16; return x.f;
}
__device__ __forceinline__ unsigned short f2bf(float f){
  union { float f; unsigned int i; } x; x.f = f;
  unsigned int r = x.i + 0x7fff + ((x.i >> 16) & 1);
  return (unsigned short)(r >> 16);
}
__device__ __forceinline__ void unpack8(uint4 v, float* o){
  o[0]=bf2f((unsigned short)(v.x)); o[1]=bf2f((unsigned short)(v.x>>16));
  o[2]=bf2f((unsigned short)(v.y)); o[3]=bf2f((unsigned short)(v.y>>16));
  o[4]=bf2f((unsigned short)(v.z)); o[5]=bf2f((unsigned short)(v.z>>16));
  o[6]=bf2f((unsigned short)(v.w)); o[7]=bf2f((unsigned short)(v.w>>16));
}
__device__ __forceinline__ uint4 pack8(const float* f){
  uint4 v;
  v.x = (unsigned)f2bf(f[0]) | ((unsigned)f2bf(f[1])<<16);
  v.y = (unsigned)f2bf(f[2]) | ((unsigned)f2bf(f[3])<<16);
  v.z = (unsigned)f2bf(f[4]) | ((unsigned)f2bf(f[5])<<16);
  v.w = (unsigned)f2bf(f[6]) | ((unsigned)f2bf(f[7])<<16);
  return v;
}
__device__ __forceinline__ void loadrow16_f32(const float* p, float* in){
  float4 a = *(const float4*)p;      float4 b = *(const float4*)(p+4);
  float4 c = *(const float4*)(p+8);  float4 d = *(const float4*)(p+12);
  in[0]=a.x; in[1]=a.y; in[2]=a.z; in[3]=a.w;
  in[4]=b.x; in[5]=b.y; in[6]=b.z; in[7]=b.w;
  in[8]=c.x; in[9]=c.y; in[10]=c.z; in[11]=c.w;
  in[12]=d.x; in[13]=d.y; in[14]=d.z; in[15]=d.w;
}
// 8 contiguous f32 * m -> bf16x8
__device__ __forceinline__ bfx8 f32x8_to_bf(const float* p, float m){
  float4 a = *(const float4*)p; float4 b = *(const float4*)(p+4);
  bfx8 r;
  r[0]=(short)f2bf(a.x*m); r[1]=(short)f2bf(a.y*m); r[2]=(short)f2bf(a.z*m); r[3]=(short)f2bf(a.w*m);
  r[4]=(short)f2bf(b.x*m); r[5]=(short)f2bf(b.y*m); r[6]=(short)f2bf(b.z*m); r[7]=(short)f2bf(b.w*m);
  return r;
}

// ---------- f32 -> packed bf16 conversion (8 elems/thread) ----------
__global__ void k_f2b(const float* __restrict__ src, unsigned short* __restrict__ dst, long n8){
  long t = (long)blockIdx.x*blockDim.x + threadIdx.x;
  if (t >= n8) return;
  const float* p = src + t*8;
  float4 a = *(const float4*)p; float4 b = *(const float4*)(p+4);
  float f[8] = {a.x,a.y,a.z,a.w,b.x,b.y,b.z,b.w};
  *(uint4*)(dst + t*8) = pack8(f);
}

// ---------- bucketed CSR build ----------
__global__ void __launch_bounds__(256) k_bcount(
    const int* __restrict__ dst, int n, int chunk, int shift, int nb,
    int* __restrict__ bkt_cnt){
  extern __shared__ int hist[];
  for (int b = threadIdx.x; b < nb; b += 256) hist[b] = 0;
  __syncthreads();
  int i0 = blockIdx.x * chunk;
  int iend = min(i0 + chunk, n);
  for (int i = i0 + threadIdx.x; i < iend; i += 256)
    atomicAdd(&hist[dst[i] >> shift], 1);
  __syncthreads();
  for (int b = threadIdx.x; b < nb; b += 256){
    int h = hist[b];
    if (h) atomicAdd(&bkt_cnt[b], h);
  }
}

__global__ void k_bscan(const int* __restrict__ bkt_cnt, int* __restrict__ bkt_base,
                        int* __restrict__ bcur, int nb){
  __shared__ int s[256];
  __shared__ int carry;
  if (threadIdx.x==0) carry = 0;
  __syncthreads();
  for (int base=0; base<nb; base+=256){
    int i = base + threadIdx.x;
    int v = (i<nb) ? bkt_cnt[i] : 0;
    s[threadIdx.x] = v; __syncthreads();
    for (int off=1; off<256; off<<=1){
      int t = (threadIdx.x>=off) ? s[threadIdx.x-off] : 0;
      __syncthreads();
      s[threadIdx.x] += t;
      __syncthreads();
    }
    int excl = s[threadIdx.x] - v + carry;
    if (i<nb){ bkt_base[i] = excl; bcur[i*16] = excl; }
    int tot = s[255];
    __syncthreads();
    if (threadIdx.x==0) carry += tot;
    __syncthreads();
  }
  if (threadIdx.x==0) bkt_base[nb] = carry;
}

// scatter with block-local counting sort; payload packed and staged in LDS
// (no global re-reads in the write phase, no write amplification).
// PACK1: payload = (local_dst << LBITS) | src  (one int)
// !PACK1: payload = int2{ (local_dst << LBITS) | src, eid }
template<int CHUNK, int NBMAX, bool PACK1, int LBITS>
__global__ void __launch_bounds__(256) k_scatter3(
    const int* __restrict__ src, const int* __restrict__ dst, int n,
    int shift, int nb, int* __restrict__ bcur, int* __restrict__ out){
  __shared__ int hist[NBMAX];   // counts -> lbase -> cursor -> run-end
  __shared__ int delta[NBMAX];  // global run base - local base
  __shared__ int s[256];
  __shared__ int carry;
  __shared__ int slotP[PACK1 ? CHUNK : 2*CHUNK];
  for (int b = threadIdx.x; b < nb; b += 256) hist[b] = 0;
  if (threadIdx.x==0) carry = 0;
  __syncthreads();
  int i0 = blockIdx.x * CHUNK;
  int iend = min(i0 + CHUNK, n);
  // phase A: histogram
  for (int i = i0 + threadIdx.x; i < iend; i += 256)
    atomicAdd(&hist[dst[i] >> shift], 1);
  __syncthreads();
  // scan -> local bases; reserve global runs; delta
  for (int base = 0; base < nb; base += 256){
    int b = base + threadIdx.x;
    int v = (b < nb) ? hist[b] : 0;
    s[threadIdx.x] = v; __syncthreads();
    for (int off=1; off<256; off<<=1){
      int t = (threadIdx.x>=off) ? s[threadIdx.x-off] : 0;
      __syncthreads();
      s[threadIdx.x] += t;
      __syncthreads();
    }
    int excl = s[threadIdx.x] - v + carry;
    int tot = s[255];
    if (b < nb){
      int g = v ? atomicAdd(&bcur[b*16], v) : 0;
      delta[b] = g - excl;
      hist[b] = excl;               // becomes the placement cursor
    }
    __syncthreads();
    if (threadIdx.x==0) carry += tot;
    __syncthreads();
  }
  // phase B: pack payload into LDS, bucket-grouped (dst/src re-read is L2-hot)
  for (int i = i0 + threadIdx.x; i < iend; i += 256){
    int d = dst[i];
    int b = d >> shift;
    int p = atomicAdd(&hist[b], 1);
    int w0 = ((d & ((1<<shift)-1)) << LBITS) | src[i];
    if (PACK1) slotP[p] = w0;
    else { slotP[2*p] = w0; slotP[2*p+1] = i; }
  }
  __syncthreads();
  // phase C: 16-lane groups stream each bucket's run to global (coalesced)
  int grp = threadIdx.x >> 4, lane16 = threadIdx.x & 15;
  for (int b = grp; b < nb; b += 16){
    int lbeg = b ? hist[b-1] : 0;   // hist is now run-ends
    int lend = hist[b];
    int dlt  = delta[b];
    for (int k = lbeg + lane16; k < lend; k += 16){
      if (PACK1) out[(size_t)(k + dlt)] = slotP[k];
      else *(int2*)(out + (size_t)(k + dlt)*2) = make_int2(slotP[2*k], slotP[2*k+1]);
    }
  }
}

// place: one block per bucket; per-row histogram + scan in LDS; rowptr slice
// written from LDS; edges placed via LDS cursors into L2-resident CSR segment.
// MODE 0: binned int  = (row<<21)|src          -> colA
// MODE 1: binned int2 = {(row<<24)|src, eid}   -> colA, colB
template<int MODE, int RLOG>
__global__ void __launch_bounds__(256) k_place3(
    const int* __restrict__ bkt_base, const int* __restrict__ binned,
    int nrows, int* __restrict__ rowptr,
    int* __restrict__ colA, int* __restrict__ colB){
  constexpr int R = 1 << RLOG;
  constexpr int K = R / 256;
  __shared__ int cnt[R];
  __shared__ int s[256];
  int rowBase = blockIdx.x << RLOG;
  int nr = min(R, nrows - rowBase);
  int beg = bkt_base[blockIdx.x], end = bkt_base[blockIdx.x+1];
  #pragma unroll
  for (int k=0;k<K;k++) cnt[threadIdx.x + k*256] = 0;
  __syncthreads();
  for (int i = beg + threadIdx.x; i < end; i += 256){
    int r = (MODE==0) ? (int)(((unsigned)binned[i]) >> 21)
                      : (int)(((unsigned)((const int2*)binned)[i].x) >> 24);
    atomicAdd(&cnt[r], 1);
  }
  __syncthreads();
  int myBase = threadIdx.x * K;
  int part = 0;
  #pragma unroll
  for (int k=0;k<K;k++) part += cnt[myBase+k];
  s[threadIdx.x] = part; __syncthreads();
  for (int off=1; off<256; off<<=1){
    int t = (threadIdx.x>=off) ? s[threadIdx.x-off] : 0;
    __syncthreads();
    s[threadIdx.x] += t;
    __syncthreads();
  }
  int run = s[threadIdx.x] - part + beg;
  #pragma unroll
  for (int k=0;k<K;k++){
    int idx = myBase + k;
    int c = cnt[idx];
    cnt[idx] = run;                       // becomes the placement cursor
    if (idx < nr) rowptr[rowBase + idx] = run;
    run += c;
  }
  if (blockIdx.x == gridDim.x-1 && threadIdx.x == 255) rowptr[nrows] = end;
  __syncthreads();
  for (int i = beg + threadIdx.x; i < end; i += 256){
    if (MODE==0){
      unsigned v = (unsigned)binned[i];
      int p = atomicAdd(&cnt[v >> 21], 1);
      colA[p] = (int)(v & 0x1FFFFFu);
    } else {
      int2 v = ((const int2*)binned)[i];
      unsigned w0 = (unsigned)v.x;
      int p = atomicAdd(&cnt[w0 >> 24], 1);
      colA[p] = (int)(w0 & 0xFFFFFFu); colB[p] = v.y;
    }
  }
}

// ---------- gather spmm (bf16 rows) ----------
// 2 threads per row, 8 channels (16B) each; 2-way unroll for gather ILP.
template<bool REMAP>
__global__ void __launch_bounds__(256) k_spmm(
    const int* __restrict__ rowptr, const int* __restrict__ col,
    const int* __restrict__ remap,
    const unsigned short* __restrict__ src, unsigned short* __restrict__ out, int nrows){
  int t = blockIdx.x*256 + threadIdx.x;
  int row = t >> 1, half = t & 1;
  if (row >= nrows) return;
  int beg = rowptr[row], end = rowptr[row+1];
  float acc[8] = {0,0,0,0,0,0,0,0};
  float acc2[8] = {0,0,0,0,0,0,0,0};
  const unsigned short* sp = src + (half<<3);
  int i = beg;
  for (; i+2 <= end; i += 2){
    int c0 = col[i], c1 = col[i+1];
    if (REMAP){ c0 = remap[c0]; c1 = remap[c1]; }
    uint4 v0 = *(const uint4*)(sp + ((size_t)c0<<4));
    uint4 v1 = *(const uint4*)(sp + ((size_t)c1<<4));
    float f0[8], f1[8]; unpack8(v0, f0); unpack8(v1, f1);
    #pragma unroll
    for (int j=0;j<8;j++){ acc[j] += f0[j]; acc2[j] += f1[j]; }
  }
  if (i < end){
    int c = col[i];
    if (REMAP) c = remap[c];
    uint4 v = *(const uint4*)(sp + ((size_t)c<<4));
    float f[8]; unpack8(v, f);
    #pragma unroll
    for (int j=0;j<8;j++) acc[j] += f[j];
  }
  #pragma unroll
  for (int j=0;j<8;j++) acc[j] += acc2[j];
  *(uint4*)(out + ((size_t)row<<4) + (half<<3)) = pack8(acc);
}

// ---------- fused 6-way projection via MFMA ----------
__global__ void __launch_bounds__(256) k_final_mfma(
    const float* __restrict__ base, const float* __restrict__ deg,
    const unsigned short* __restrict__ s2, const unsigned short* __restrict__ s3,
    const unsigned short* __restrict__ s4, const unsigned short* __restrict__ s5,
    const float* __restrict__ W, const float* __restrict__ Bb,
    float* __restrict__ hout, int nrows){
  int lane = threadIdx.x & 63;
  int l15 = lane & 15;
  int quad = lane >> 4;          // 0..3
  int kbase = quad * 8;          // 0,8,16,24 within the 32-wide k-block
  int slocal = kbase >> 4;       // source select within k-block (0 or 1)
  int k0 = kbase & 15;           // channel offset within source (0 or 8)

  bfx8 bh[3][2], bl[3][2];
  #pragma unroll
  for (int kb=0; kb<3; ++kb){
    int s = kb*2 + slocal;
    #pragma unroll
    for (int t=0;t<2;++t){
      int o = t*16 + l15;
      const float* wp = W + s*512 + o*16 + k0;
      bfx8 hi, lo;
      #pragma unroll
      for (int j=0;j<8;j++){
        float w0 = wp[j];
        unsigned short h = f2bf(w0);
        unsigned short l2 = f2bf(w0 - bf2f(h));
        hi[j] = (short)h; lo[j] = (short)l2;
      }
      bh[kb][t] = hi; bl[kb][t] = lo;
    }
  }
  float bias0 = 0.f, bias1 = 0.f;
  #pragma unroll
  for (int s=0;s<6;s++){ bias0 += Bb[s*32 + l15]; bias1 += Bb[s*32 + 16 + l15]; }

  int ntiles = (nrows + 15) >> 4;
  int wstart = (blockIdx.x<<2) + (threadIdx.x>>6);
  int wstep  = gridDim.x<<2;
  for (int tile = wstart; tile < ntiles; tile += wstep){
    int R0 = tile << 4;
    int row = R0 + l15;
    int rowc = min(row, nrows-1);
    size_t ro = (size_t)rowc*16 + k0;
    float m = slocal ? deg[rowc] : 1.f;
    bfx8 a0 = f32x8_to_bf(base + ro, m);
    bfx8 a1 = *(const bfx8*)((slocal ? s3 : s2) + ro);
    bfx8 a2 = *(const bfx8*)((slocal ? s5 : s4) + ro);
    f32x4 c0 = {bias0,bias0,bias0,bias0};
    f32x4 c1 = {bias1,bias1,bias1,bias1};
    c0 = __builtin_amdgcn_mfma_f32_16x16x32_bf16(a0, bh[0][0], c0, 0,0,0);
    c1 = __builtin_amdgcn_mfma_f32_16x16x32_bf16(a0, bh[0][1], c1, 0,0,0);
    c0 = __builtin_amdgcn_mfma_f32_16x16x32_bf16(a1, bh[1][0], c0, 0,0,0);
    c1 = __builtin_amdgcn_mfma_f32_16x16x32_bf16(a1, bh[1][1], c1, 0,0,0);
    c0 = __builtin_amdgcn_mfma_f32_16x16x32_bf16(a2, bh[2][0], c0, 0,0,0);
    c1 = __builtin_amdgcn_mfma_f32_16x16x32_bf16(a2, bh[2][1], c1, 0,0,0);
    c0 = __builtin_amdgcn_mfma_f32_16x16x32_bf16(a0, bl[0][0], c0, 0,0,0);
    c1 = __builtin_amdgcn_mfma_f32_16x16x32_bf16(a0, bl[0][1], c1, 0,0,0);
    c0 = __builtin_amdgcn_mfma_f32_16x16x32_bf16(a1, bl[1][0], c0, 0,0,0);
    c1 = __builtin_amdgcn_mfma_f32_16x16x32_bf16(a1, bl[1][1], c1, 0,0,0);
    c0 = __builtin_amdgcn_mfma_f32_16x16x32_bf16(a2, bl[2][0], c0, 0,0,0);
    c1 = __builtin_amdgcn_mfma_f32_16x16x32_bf16(a2, bl[2][1], c1, 0,0,0);
    #pragma unroll
    for (int j=0;j<4;j++){
      int r = R0 + quad*4 + j;
      if (r < nrows) hout[(size_t)r*16 + l15] = c0[j] + fmaxf(c1[j], 0.f);
    }
  }
}

// ---------- BN stats reduction over a row region ----------
__global__ void __launch_bounds__(256) k_red(
    const float* __restrict__ h, int nrows, float* __restrict__ stats){
  __shared__ float redS[4][16];
  __shared__ float redQ[4][16];
  float ssum[16], ssq[16];
  #pragma unroll
  for (int c=0;c<16;c++){ ssum[c]=0.f; ssq[c]=0.f; }
  for (long r = (long)blockIdx.x*256 + threadIdx.x; r < nrows; r += (long)gridDim.x*256){
    float in[16];
    loadrow16_f32(h + r*16, in);
    #pragma unroll
    for (int c=0;c<16;c++){ ssum[c] += in[c]; ssq[c] += in[c]*in[c]; }
  }
  int lane = threadIdx.x & 63, wid = threadIdx.x >> 6;
  #pragma unroll
  for (int c=0;c<16;c++){
    float s = ssum[c], q = ssq[c];
    for (int off=32; off; off>>=1){ s += __shfl_xor(s, off, 64); q += __shfl_xor(q, off, 64); }
    if (lane==0){ redS[wid][c] = s; redQ[wid][c] = q; }
  }
  __syncthreads();
  if (threadIdx.x < 16){
    float s=0.f, q=0.f;
    #pragma unroll
    for (int w4=0; w4<4; w4++){ s += redS[w4][threadIdx.x]; q += redQ[w4][threadIdx.x]; }
    atomicAdd(&stats[threadIdx.x], s);
    atomicAdd(&stats[16 + threadIdx.x], q);
  }
}

__global__ void k_stats(const float* __restrict__ st,
                        const float* __restrict__ wx, const float* __restrict__ bx,
                        const float* __restrict__ wy, const float* __restrict__ by,
                        float* __restrict__ prm, int nx, int ny){
  int c = threadIdx.x;
  if (c < 16){
    float m  = st[c]/(float)nx;
    float v  = st[16+c]/(float)nx - m*m;
    float sc = wx[c] * rsqrtf(v + 1e-5f);
    prm[c] = sc; prm[16+c] = bx[c] - m*sc;
    float m2  = st[32+c]/(float)ny;
    float v2  = st[48+c]/(float)ny - m2*m2;
    float sc2 = wy[c] * rsqrtf(v2 + 1e-5f);
    prm[32+c] = sc2; prm[48+c] = by[c] - m2*sc2;
  }
}

__global__ void k_norm(float* __restrict__ out, const float* __restrict__ prm,
                       long nx, long ntot){
  long g = ((long)blockIdx.x*256 + threadIdx.x) * 8;
  if (g >= ntot) return;
  const float* p = (g < nx) ? prm : prm + 32;
  int cbase = (int)(g & 15);
  float4 a = *(float4*)(out + g);
  float4 b = *(float4*)(out + g + 4);
  float f[8] = {a.x,a.y,a.z,a.w,b.x,b.y,b.z,b.w};
  #pragma unroll
  for (int j=0;j<8;j++){ int c = cbase + j; f[j] = f[j]*p[c] + p[16+c]; }
  *(float4*)(out + g)     = make_float4(f[0],f[1],f[2],f[3]);
  *(float4*)(out + g + 4) = make_float4(f[4],f[5],f[6],f[7]);
}

// ---------- host ----------
extern "C" void kernel_launch(void* const* d_in, const int* in_sizes, int n_in,
                              void* d_out, int out_size, void* d_ws, size_t ws_size,
                              hipStream_t stream){
  const float* x      = (const float*)d_in[0];
  const float* y      = (const float*)d_in[1];
  const float* deg_g  = (const float*)d_in[2];
  const float* deg_lg = (const float*)d_in[3];
  const float* thW    = (const float*)d_in[4];
  const float* thB    = (const float*)d_in[5];
  const float* gaW    = (const float*)d_in[6];
  const float* gaB    = (const float*)d_in[7];
  const float* bnxw   = (const float*)d_in[8];
  const float* bnxb   = (const float*)d_in[9];
  const float* bnyw   = (const float*)d_in[10];
  const float* bnyb   = (const float*)d_in[11];
  const int* src_g   = (const int*)d_in[12];
  const int* dst_g   = (const int*)d_in[13];
  const int* src_lg  = (const int*)d_in[14];
  const int* dst_lg  = (const int*)d_in[15];
  const int* eid2nid = (const int*)d_in[16];

  const int N  = in_sizes[2];   // deg_g is (N,1)   (=100000: src fits 17 bits)
  const int E  = in_sizes[3];   // deg_lg is (E,1)  (=1.6M < 2^21: packing ok)
  const int EL = in_sizes[14];  // src_lg

  char* w = (char*)d_ws;
  auto alloc = [&](size_t bytes)->void*{
    void* p = (void*)w; w += (bytes + 255) & ~(size_t)255; return p;
  };
  int* g_rowptr   = (int*)alloc((size_t)(N+1)*4);
  int* g_col_src  = (int*)alloc((size_t)E*4);
  int* g_col_eid  = (int*)alloc((size_t)E*4);
  int* lg_rowptr  = (int*)alloc((size_t)(E+1)*4);
  int* lg_col     = (int*)alloc((size_t)EL*4);
  int* bcur       = (int*)alloc((size_t)1024*16*4);  // padded bucket cursors
  int* bkt_cnt_g  = (int*)alloc(1024*4);
  int* bkt_base_g = (int*)alloc(1025*4);
  int* bkt_cnt_l  = (int*)alloc(1024*4);
  int* bkt_base_l = (int*)alloc(1025*4);
  float* stats    = (float*)alloc(64*4);
  float* prm      = (float*)alloc(64*4);
  unsigned short* xb  = (unsigned short*)alloc((size_t)N*16*2);   // bf16 copy of x
  unsigned short* nz1 = (unsigned short*)alloc((size_t)N*16*2);
  unsigned short* nz2 = (unsigned short*)alloc((size_t)N*16*2);
  unsigned short* nz3 = (unsigned short*)alloc((size_t)N*16*2);
  unsigned short* nz4 = (unsigned short*)alloc((size_t)N*16*2);
  unsigned short* nyx = (unsigned short*)alloc((size_t)N*16*2);
  unsigned short* eb1 = (unsigned short*)alloc((size_t)E*16*2);
  unsigned short* eb2 = (unsigned short*)alloc((size_t)E*16*2);
  unsigned short* eb3 = (unsigned short*)alloc((size_t)E*16*2);  // B^3 y, then xy_agg
  unsigned short* yb  = (unsigned short*)alloc((size_t)E*16*2);  // bf16 copy of y; later reused as eb4
  unsigned short* eb4 = yb;            // alias: yb dead before eb4 is written
  int* binned_g = (int*)eb1;           // alias: E*8B   <= eb1 (E*32B)
  int* binned_l = (int*)eb2;           // alias: EL*4B  <= eb2 (E*32B)

  hipMemsetAsync(bkt_cnt_g, 0, 1024*4, stream);
  hipMemsetAsync(bkt_cnt_l, 0, 1024*4, stream);
  hipMemsetAsync(stats, 0, 64*4, stream);

  // ---- bf16 copies of x and y ----
  long nx8 = (long)N*16/8, ny8 = (long)E*16/8;
  k_f2b<<<(int)((nx8+255)/256), 256, 0, stream>>>(x, xb, nx8);
  k_f2b<<<(int)((ny8+255)/256), 256, 0, stream>>>(y, yb, ny8);

  // ---- bucketed CSR build: g (256 rows/bucket), payload int2 {(ld<<24)|src, eid} ----
  const int RLOG_G = 8;
  int nb_g = (N + (1<<RLOG_G) - 1) >> RLOG_G;            // ~391 buckets
  k_bcount<<<(E+8191)/8192, 256, (size_t)nb_g*4, stream>>>(
      dst_g, E, 8192, RLOG_G, nb_g, bkt_cnt_g);
  k_bscan<<<1, 256, 0, stream>>>(bkt_cnt_g, bkt_base_g, bcur, nb_g);
  k_scatter3<4096, 512, false, 24><<<(E+4095)/4096, 256, 0, stream>>>(
      src_g, dst_g, E, RLOG_G, nb_g, bcur, binned_g);
  k_place3<1, RLOG_G><<<nb_g, 256, 0, stream>>>(
      bkt_base_g, binned_g, N, g_rowptr, g_col_src, g_col_eid);

  // ---- bucketed CSR build: lg (2048 rows/bucket), payload int (ld<<21)|src ----
  const int RLOG_L = 11;
  int nb_l = (E + (1<<RLOG_L) - 1) >> RLOG_L;            // ~782 buckets
  k_bcount<<<(EL+16383)/16384, 256, (size_t)nb_l*4, stream>>>(
      dst_lg, EL, 16384, RLOG_L, nb_l, bkt_cnt_l);
  k_bscan<<<1, 256, 0, stream>>>(bkt_cnt_l, bkt_base_l, bcur, nb_l);
  k_scatter3<8192, 1024, true, 21><<<(EL+8191)/8192, 256, 0, stream>>>(
      src_lg, dst_lg, EL, RLOG_L, nb_l, bcur, binned_l);
  k_place3<0, RLOG_L><<<nb_l, 256, 0, stream>>>(
      bkt_base_l, binned_l, E, lg_rowptr, lg_col, (int*)nullptr);

  // ---- spmms that read yb first (so eb4 can reuse yb's buffer) ----
  int gs = (2*N+255)/256;
  int es = (2*E+255)/256;
  k_spmm<false><<<es, 256, 0, stream>>>(lg_rowptr, lg_col, nullptr, yb,  eb1, E);   // B y
  k_spmm<false><<<gs, 256, 0, stream>>>(g_rowptr, g_col_eid, nullptr, yb, nyx, N);  // sum_e y by dst
  // ---- node branch chain ----
  k_spmm<false><<<gs, 256, 0, stream>>>(g_rowptr, g_col_src, nullptr, xb,  nz1, N); // A x
  k_spmm<false><<<gs, 256, 0, stream>>>(g_rowptr, g_col_src, nullptr, nz1, nz2, N); // A^2 x
  k_spmm<false><<<gs, 256, 0, stream>>>(g_rowptr, g_col_src, nullptr, nz2, nz3, N); // A^3 x
  k_spmm<false><<<gs, 256, 0, stream>>>(g_rowptr, g_col_src, nullptr, nz3, nz4, N); // A^4 x
  // ---- edge branch chain (yb dead after eb1/nyx; eb4 overwrites it) ----
  k_spmm<false><<<es, 256, 0, stream>>>(lg_rowptr, lg_col, nullptr, eb1, eb2, E);   // B^2 y
  k_spmm<false><<<es, 256, 0, stream>>>(lg_rowptr, lg_col, nullptr, eb2, eb3, E);   // B^3 y
  k_spmm<false><<<es, 256, 0, stream>>>(lg_rowptr, lg_col, nullptr, eb3, eb4, E);   // B^4 y
  k_spmm<true><<<es, 256, 0, stream>>>(lg_rowptr, lg_col, eid2nid, xb,  eb3, E);    // B (x[eid2nid])

  // ---- fused projections + h (MFMA) ----
  float* outp = (float*)d_out;
  int tg = (N + 15) >> 4;  int bg2 = (tg + 3) / 4;  if (bg2 > 2048) bg2 = 2048;
  int te = (E + 15) >> 4;  int be2 = (te + 3) / 4;  if (be2 > 2048) be2 = 2048;
  k_final_mfma<<<bg2, 256, 0, stream>>>(x, deg_g, nyx, nz1, nz2, nz4,
                                        thW, thB, outp, N);
  k_final_mfma<<<be2, 256, 0, stream>>>(y, deg_lg, eb3, eb1, eb2, eb4,
                                        gaW, gaB, outp + (size_t)N*16, E);

  // ---- BN stats + normalize ----
  k_red<<<512, 256, 0, stream>>>(outp, N, stats);
  k_red<<<512, 256, 0, stream>>>(outp + (size_t)N*16, E, stats + 32);
  k_stats<<<1, 64, 0, stream>>>(stats, bnxw, bnxb, bnyw, bnyb, prm, N, E);
  long ntot = (long)(N + E) * 16;
  k_norm<<<(int)((ntot/8 + 255)/256), 256, 0, stream>>>(outp, prm, (long)N*16, ntot);
}